// Round 6
// baseline (84.945 us; speedup 1.0000x reference)
//
#include <hip/hip_runtime.h>
#include <hip/hip_bf16.h>

#define BSZ  131072
#define DIM  256
#define BM   64
#define NT   512            // 8 waves; wave w owns output cols [w*32, w*32+32)
#define GRID (BSZ / BM)     // 2048

typedef __attribute__((ext_vector_type(8))) short bf16x8;
typedef __attribute__((ext_vector_type(4))) float f32x4;
typedef __attribute__((ext_vector_type(2))) unsigned int u32x2;
typedef __attribute__((ext_vector_type(4))) unsigned short u16x4;

// LDS: z tiles only, double-buffered. Row = 32 bf16 = 64B, padded to 80B
// (bank period 5 -> b128 fragment reads are <=2-way aliased = free).
#define ZROWB 80
#define ZB(b) ((b) * (BM * ZROWB))   // 5120 per buffer

__device__ __forceinline__ unsigned short f2bf(float f) {
  unsigned u = __builtin_bit_cast(unsigned, f);
  return (unsigned short)((u + 0x7FFFu + ((u >> 16) & 1u)) >> 16);
}
__device__ __forceinline__ unsigned cvt_pk(float lo, float hi) {
  unsigned r;
  asm("v_cvt_pk_bf16_f32 %0, %1, %2" : "=v"(r) : "v"(lo), "v"(hi));
  return r;
}

// ---------------- prep: f32 W -> bf16 wT, K-major: wT[kb][j][kk], kb=k/32 ----------------
__global__ void prep_kernel(const float* __restrict__ Wmu, const float* __restrict__ Wsd,
                            unsigned short* __restrict__ wm, unsigned short* __restrict__ wsd) {
  const int tg = blockIdx.x * 256 + threadIdx.x;   // 16384 threads
  const int j  = tg >> 6, kq = tg & 63;            // row j, k-quad (k0 = kq*4)
  const int dst = ((kq >> 3) << 13) + (j << 5) + ((kq & 7) << 2);
  f32x4 a = *(const f32x4*)(Wmu + j * 256 + kq * 4);
  f32x4 b = *(const f32x4*)(Wsd + j * 256 + kq * 4);
  u16x4 pa, pb;
#pragma unroll
  for (int e = 0; e < 4; ++e) { pa[e] = f2bf(a[e]); pb[e] = f2bf(b[e]); }
  *(u16x4*)(wm + dst)  = pa;
  *(u16x4*)(wsd + dst) = pb;
}

// ---------------- main fused kernel ----------------
__global__ __launch_bounds__(NT, 4)
void main_kernel(const float* __restrict__ z,
                 const unsigned short* __restrict__ wm,
                 const unsigned short* __restrict__ wsd,
                 const float* __restrict__ bmu,
                 const float* __restrict__ bsd,
                 float* __restrict__ out,
                 float* __restrict__ partials) {
  __shared__ unsigned char smem[2 * BM * ZROWB];   // 10240 B
  __shared__ float redbuf[8];
  const int t = threadIdx.x, lane = t & 63, w = t >> 6;
  const int bm = blockIdx.x;

  // z global source (coalesced: 8 lanes x 16B contiguous per row)
  const float* zsrc = z + (size_t)(bm * BM + (t >> 3)) * DIM + (t & 7) * 4;
  const int zw = (t >> 3) * ZROWB + (t & 7) * 8;    // z ds_write byte offset

  // W fragment sources: direct global, fully coalesced in K-major wT.
  // elem = kb*8192 + (w*32 + mi*16 + (lane&15))*32 + (lane>>4)*8
  const int wlo = (lane & 15) * 32 + (lane >> 4) * 8;
  const unsigned short* wmb = wm  + w * 1024 + wlo;   // + mi*512 + kb*8192
  const unsigned short* wsb = wsd + w * 1024 + wlo;

  // z fragment read offsets: row R=nj*16+(lane&15), 16B unit g=lane>>4
  const int zro = (lane & 15) * ZROWB + (lane >> 4) * 16;   // + nj*16*ZROWB + buf

  f32x4 accm[2][4], accl[2][4];   // [mi][nj]
#pragma unroll
  for (int mi = 0; mi < 2; ++mi)
#pragma unroll
    for (int nj = 0; nj < 4; ++nj) { accm[mi][nj] = (f32x4)0.0f; accl[mi][nj] = (f32x4)0.0f; }

  f32x4 zr0, zr1;

  // ---- prologue: z(0),z(1) in regs; write z(0) to LDS buf0 ----
  zr0 = *(const f32x4*)zsrc;
  zr1 = *(const f32x4*)(zsrc + 32);
  {
    u32x2 p;
    p[0] = cvt_pk(zr0[0], zr0[1]);
    p[1] = cvt_pk(zr0[2], zr0[3]);
    *(u32x2*)(smem + ZB(0) + zw) = p;
  }
  asm volatile("s_waitcnt lgkmcnt(0)" ::: "memory");
  __builtin_amdgcn_sched_barrier(0);
  __builtin_amdgcn_s_barrier();
  __builtin_amdgcn_sched_barrier(0);

  // ---- K loop: 8 iters, fully unrolled, one raw barrier per iter ----
#pragma unroll
  for (int it = 0; it < 8; ++it) {
    const int kb = it * 8192;
    // W fragments for this iter: 4 coalesced b128 loads (L2-resident)
    bf16x8 wcm[2], wcs[2];
    wcm[0] = *(const bf16x8*)(wmb + kb);
    wcm[1] = *(const bf16x8*)(wmb + kb + 512);
    wcs[0] = *(const bf16x8*)(wsb + kb);
    wcs[1] = *(const bf16x8*)(wsb + kb + 512);

    // z global prefetch (dist-2)
    if (it < 6) {
      f32x4 v = *(const f32x4*)(zsrc + (it + 2) * 32);
      if ((it & 1) == 0) zr0 = v; else zr1 = v;
    }

    // z fragments from LDS
    const unsigned char* zb = smem + ZB(it & 1);
    bf16x8 zf[4];
#pragma unroll
    for (int nj = 0; nj < 4; ++nj)
      zf[nj] = *(const bf16x8*)(zb + nj * 16 * ZROWB + zro);

#pragma unroll
    for (int mi = 0; mi < 2; ++mi)
#pragma unroll
      for (int nj = 0; nj < 4; ++nj) {
        accm[mi][nj] = __builtin_amdgcn_mfma_f32_16x16x32_bf16(wcm[mi], zf[nj], accm[mi][nj], 0, 0, 0);
        accl[mi][nj] = __builtin_amdgcn_mfma_f32_16x16x32_bf16(wcs[mi], zf[nj], accl[mi][nj], 0, 0, 0);
      }

    if (it < 7) {
      // write z(it+1) into buf((it+1)&1); its last readers finished at iter it-1
      const f32x4 v = (it & 1) ? zr0 : zr1;   // zreg[(it+1)&1]
      u32x2 p;
      p[0] = cvt_pk(v[0], v[1]);
      p[1] = cvt_pk(v[2], v[3]);
      *(u32x2*)(smem + ZB((it + 1) & 1) + zw) = p;
      asm volatile("s_waitcnt lgkmcnt(0)" ::: "memory");
      __builtin_amdgcn_sched_barrier(0);
      __builtin_amdgcn_s_barrier();
      __builtin_amdgcn_sched_barrier(0);
    }
  }

  // ---- epilogue: bias + relu + KL + vectorized f32x4 stores ----
  float klp = 0.0f;
#pragma unroll
  for (int mi = 0; mi < 2; ++mi) {
    const int colb = w * 32 + mi * 16 + ((lane >> 4) << 2);
    const f32x4 b4m = *(const f32x4*)(bmu + colb);
    const f32x4 b4s = *(const f32x4*)(bsd + colb);
#pragma unroll
    for (int nj = 0; nj < 4; ++nj) {
      const size_t row = (size_t)(bm * BM + nj * 16 + (lane & 15));
      f32x4 mu4;
#pragma unroll
      for (int r = 0; r < 4; ++r) {
        float mu = fmaxf(accm[mi][nj][r] + b4m[r], 0.0f);
        float ls = fmaxf(accl[mi][nj][r] + b4s[r], 0.0f);
        float iv = __expf(-2.0f * ls);
        klp += fmaf(mu * mu, iv, iv) + 2.0f * ls;   // (1+mu^2)*iv + 2*ls; -1 folded below
        mu4[r] = mu;
      }
      *(f32x4*)(out + row * DIM + colb) = mu4;
    }
  }
  klp = 0.5f * (klp - 32.0f);   // 32 elements per lane

#pragma unroll
  for (int off = 32; off; off >>= 1) klp += __shfl_down(klp, off);
  if (lane == 0) redbuf[w] = klp;
  __syncthreads();
  if (t == 0) {
    float s = 0.0f;
#pragma unroll
    for (int i = 0; i < 8; ++i) s += redbuf[i];
    partials[bm] = s;
  }
}

// ---------------- finalize ----------------
__global__ void fin_kernel(const float* __restrict__ partials, float* __restrict__ out) {
  __shared__ double red[256];
  double s = 0.0;
  for (int i = threadIdx.x; i < GRID; i += 256) s += (double)partials[i];
  red[threadIdx.x] = s;
  __syncthreads();
  for (int st = 128; st > 0; st >>= 1) {
    if ((int)threadIdx.x < st) red[threadIdx.x] += red[threadIdx.x + st];
    __syncthreads();
  }
  if (threadIdx.x == 0) out[(size_t)BSZ * DIM] = (float)(red[0] / (double)BSZ);
}

// ---------------- launch ----------------
// ws: [0,8192) float partials[2048]; [8192,+128K) wT_mu; [139264,+128K) wT_sd. Total 270336 B.
extern "C" void kernel_launch(void* const* d_in, const int* in_sizes, int n_in,
                              void* d_out, int out_size, void* d_ws, size_t ws_size,
                              hipStream_t stream) {
  const float* z   = (const float*)d_in[0];
  const float* Wmu = (const float*)d_in[1];
  const float* bmu = (const float*)d_in[2];
  const float* Wsd = (const float*)d_in[3];
  const float* bsd = (const float*)d_in[4];
  float* out = (float*)d_out;

  float* partials     = (float*)d_ws;
  unsigned short* wm  = (unsigned short*)((char*)d_ws + 8192);
  unsigned short* wsd = wm + DIM * DIM;

  prep_kernel<<<64, 256, 0, stream>>>(Wmu, Wsd, wm, wsd);
  main_kernel<<<GRID, NT, 0, stream>>>(z, wm, wsd, bmu, bsd, out, partials);
  fin_kernel<<<1, 256, 0, stream>>>(partials, out);
}